// Round 1
// baseline (40.656 us; speedup 1.0000x reference)
//
#include <hip/hip_runtime.h>
#include <math.h>

#define NCLS 80
#define RMAX 16
#define BB 8
#define LL 21504
#define NN (BB * LL)

// ---------------------------------------------------------------------------
// Kernel 1: detect fg_mask storage layout (bool/int8 vs int32 vs float32) and
// zero the loss accumulators. Reads only the first NN/4 32-bit words, which is
// valid under every candidate layout (NN bytes is the minimum buffer size).
//   flag 0 -> int32 (values 0/1)
//   flag 1 -> 1-byte bool/int8
//   flag 2 -> float32 (0.0 / 1.0)
// ---------------------------------------------------------------------------
__global__ __launch_bounds__(1024) void detect_zero_kernel(
    const unsigned int* __restrict__ fgw, unsigned int* wsu, float* wsf) {
  unsigned int acc = 0;
  const int nwords = NN / 4;  // 43008 words = 172032 bytes, always in-bounds
  for (int i = threadIdx.x; i < nwords; i += 1024) acc |= fgw[i];
#pragma unroll
  for (int o = 32; o >= 1; o >>= 1) acc |= __shfl_xor(acc, o);
  __shared__ unsigned int sm[16];
  const int wid = threadIdx.x >> 6;
  if ((threadIdx.x & 63) == 0) sm[wid] = acc;
  __syncthreads();
  if (threadIdx.x == 0) {
    unsigned int o = 0;
#pragma unroll
    for (int i = 0; i < 16; ++i) o |= sm[i];
    unsigned int flag;
    if (o == 0x3F800000u) flag = 2u;        // all words are 0.0f / 1.0f
    else if ((o & ~1u) != 0u) flag = 1u;    // bits beyond LSB -> packed bytes
    else flag = 0u;                          // 0/1 int32 words
    wsu[2] = flag;
    wsf[0] = 0.f;
    wsf[1] = 0.f;
  }
}

// ---------------------------------------------------------------------------
// Kernel 2: per-element loss contributions, block-reduced, atomically added.
// One thread per (b,l). Non-fg threads contribute 0 and skip all heavy work.
// ---------------------------------------------------------------------------
__global__ __launch_bounds__(256) void loss_kernel(
    const float* __restrict__ pred_dist,
    const float* __restrict__ pred_bboxes,
    const float* __restrict__ pred_angles,
    const float* __restrict__ anchor_points,
    const float* __restrict__ target_bboxes,
    const float* __restrict__ target_angles,
    const float* __restrict__ target_scores,
    const void* __restrict__ fgp,
    const unsigned int* __restrict__ wsu,
    float* __restrict__ wsf) {
  const int idx = blockIdx.x * 256 + threadIdx.x;  // grid sized exactly to NN
  float ci = 0.f, cd = 0.f;

  const unsigned int flag = wsu[2];
  bool fg;
  if (flag == 2u)      fg = ((const float*)fgp)[idx] != 0.f;
  else if (flag == 1u) fg = ((const unsigned char*)fgp)[idx] != 0;
  else                 fg = ((const int*)fgp)[idx] != 0;

  if (fg) {
    const int l = idx % LL;
    const float4 pb = ((const float4*)pred_bboxes)[idx];
    const float4 tb = ((const float4*)target_bboxes)[idx];
    const float kDeg2Rad = 3.14159265358979323846f / 180.f;
    const float pa = pred_angles[idx] * kDeg2Rad;
    const float ta = target_angles[idx] * kDeg2Rad;

    // --- corners of both boxes (CCW) ---
    const float cp = cosf(pa), sp = sinf(pa);
    const float ct = cosf(ta), st = sinf(ta);
    const float txs[4] = {0.5f, -0.5f, -0.5f, 0.5f};
    const float tys[4] = {0.5f, 0.5f, -0.5f, -0.5f};
    float c1x[4], c1y[4], c2x[4], c2y[4];
#pragma unroll
    for (int k = 0; k < 4; ++k) {
      float cx = txs[k] * pb.z, cy = tys[k] * pb.w;
      c1x[k] = cx * cp - cy * sp + pb.x;
      c1y[k] = cx * sp + cy * cp + pb.y;
      cx = txs[k] * tb.z; cy = tys[k] * tb.w;
      c2x[k] = cx * ct - cy * st + tb.x;
      c2y[k] = cx * st + cy * ct + tb.y;
    }

    // --- Sutherland-Hodgman: clip box1 by box2's 4 half-planes ---
    float px_[8], py_[8], qx_[8], qy_[8];
#pragma unroll
    for (int k = 0; k < 4; ++k) { px_[k] = c1x[k]; py_[k] = c1y[k]; }
    int n = 4;
    for (int j = 0; j < 4; ++j) {
      const float rx = c2x[j], ry = c2y[j];
      const float ex = c2x[(j + 1) & 3] - rx, ey = c2y[(j + 1) & 3] - ry;
      int m = 0;
      for (int i = 0; i < n; ++i) {
        const int ip = (i + 1 == n) ? 0 : i + 1;
        const float x0 = px_[i], y0 = py_[i];
        const float x1 = px_[ip], y1 = py_[ip];
        const float dc = ex * (y0 - ry) - ey * (x0 - rx);
        const float dn = ex * (y1 - ry) - ey * (x1 - rx);
        const bool in0 = dc >= 0.f, in1 = dn >= 0.f;
        if (in0) { qx_[m] = x0; qy_[m] = y0; ++m; }
        if (in0 != in1) {
          const float t = dc / (dc - dn);
          qx_[m] = x0 + t * (x1 - x0);
          qy_[m] = y0 + t * (y1 - y0);
          ++m;
        }
      }
      n = m;
      for (int i = 0; i < n; ++i) { px_[i] = qx_[i]; py_[i] = qy_[i]; }
      if (n == 0) break;
    }
    float a2s = 0.f;
    for (int i = 0; i < n; ++i) {
      const int ip = (i + 1 == n) ? 0 : i + 1;
      a2s += px_[i] * py_[ip] - px_[ip] * py_[i];
    }
    const float inter = 0.5f * fabsf(a2s);
    const float a1 = pb.z * pb.w, a2 = tb.z * tb.w;
    const float iou = fmaxf(inter / (a1 + a2 - inter + 1e-8f), 1e-6f);
    const float iou_loss = 1.f - iou;

    // --- bbox_weight = sum over 80 target scores ---
    const float4* sp4 = (const float4*)(target_scores + (size_t)idx * NCLS);
    float bw = 0.f;
#pragma unroll
    for (int k = 0; k < NCLS / 4; ++k) {
      const float4 v = sp4[k];
      bw += (v.x + v.y) + (v.z + v.w);
    }

    // --- DFL ---
    const float ax = anchor_points[2 * l], ay = anchor_points[2 * l + 1];
    float dists[4];
    dists[0] = fminf(fmaxf(ax - tb.x, 0.f), 15.99f);
    dists[1] = fminf(fmaxf(ay - tb.y, 0.f), 15.99f);
    dists[2] = fminf(fmaxf(tb.z - ax, 0.f), 15.99f);
    dists[3] = fminf(fmaxf(tb.w - ay, 0.f), 15.99f);
    const float* dr = pred_dist + (size_t)idx * 68;
    float dfl = 0.f;
#pragma unroll
    for (int s = 0; s < 4; ++s) {
      const float* row = dr + s * 17;
      float vv[17];
#pragma unroll
      for (int k = 0; k < 17; ++k) vv[k] = row[k];
      float mx = vv[0];
#pragma unroll
      for (int k = 1; k < 17; ++k) mx = fmaxf(mx, vv[k]);
      float se = 0.f;
#pragma unroll
      for (int k = 0; k < 17; ++k) se += expf(vv[k] - mx);
      const float lz = mx + logf(se);
      const float t = dists[s];
      int tl = (int)t;
      tl = tl < 0 ? 0 : (tl > RMAX - 1 ? RMAX - 1 : tl);
      const float wl = (float)(tl + 1) - t;
      const float wr = 1.f - wl;
      // dynamic index: re-read from global (L1 hit) to avoid register spill
      dfl -= (row[tl] - lz) * wl + (row[tl + 1] - lz) * wr;
    }
    dfl *= 0.25f;

    ci = iou_loss * bw;
    cd = dfl * bw;
  }

  // --- block reduction: wave shfl + LDS across 4 waves + 2 atomics ---
#pragma unroll
  for (int o = 32; o >= 1; o >>= 1) {
    ci += __shfl_xor(ci, o);
    cd += __shfl_xor(cd, o);
  }
  __shared__ float si[4], sd[4];
  const int wid = threadIdx.x >> 6;
  if ((threadIdx.x & 63) == 0) { si[wid] = ci; sd[wid] = cd; }
  __syncthreads();
  if (threadIdx.x == 0) {
    atomicAdd(&wsf[0], (si[0] + si[1]) + (si[2] + si[3]));
    atomicAdd(&wsf[1], (sd[0] + sd[1]) + (sd[2] + sd[3]));
  }
}

// ---------------------------------------------------------------------------
// Kernel 3: finalize
// ---------------------------------------------------------------------------
__global__ void finalize_kernel(const float* __restrict__ wsf,
                                const float* __restrict__ tss_p,
                                float* __restrict__ out) {
  const float tss = tss_p[0];
  const float denom = (tss == 0.f) ? 1.f : tss;
  out[0] = wsf[0] / denom;
  out[1] = wsf[1] / denom;
}

extern "C" void kernel_launch(void* const* d_in, const int* in_sizes, int n_in,
                              void* d_out, int out_size, void* d_ws, size_t ws_size,
                              hipStream_t stream) {
  const float* pred_dist      = (const float*)d_in[0];
  const float* pred_bboxes    = (const float*)d_in[1];
  const float* pred_angles    = (const float*)d_in[2];
  const float* anchor_points  = (const float*)d_in[3];
  const float* target_bboxes  = (const float*)d_in[4];
  const float* target_angles  = (const float*)d_in[5];
  const float* target_scores  = (const float*)d_in[6];
  const float* tss            = (const float*)d_in[7];
  const void*  fgp            = d_in[8];

  float* wsf = (float*)d_ws;
  unsigned int* wsu = (unsigned int*)d_ws;
  float* out = (float*)d_out;

  detect_zero_kernel<<<1, 1024, 0, stream>>>((const unsigned int*)fgp, wsu, wsf);
  loss_kernel<<<NN / 256, 256, 0, stream>>>(pred_dist, pred_bboxes, pred_angles,
                                            anchor_points, target_bboxes,
                                            target_angles, target_scores, fgp,
                                            wsu, wsf);
  finalize_kernel<<<1, 1, 0, stream>>>(wsf, tss, out);
}

// Round 2
// 34.796 us; speedup vs baseline: 1.1684x; 1.1684x over previous
//
#include <hip/hip_runtime.h>
#include <math.h>

#define NCLS 80
#define RMAX 16
#define BB 8
#define LL 21504
#define NN (BB * LL)

// ---------------------------------------------------------------------------
// Kernel 1: detect fg_mask storage layout (bool/int8 vs int32 vs float32) and
// zero the loss accumulators. Scans the first 16384 32-bit words (64 KB) --
// in-bounds under every candidate layout (min buffer = NN bytes = 168 KB).
// At ~10% true density every layout shows >1000 true elements in this window.
//   flag 0 -> int32 (values 0/1)
//   flag 1 -> 1-byte bool/int8
//   flag 2 -> float32 (0.0 / 1.0)
// ---------------------------------------------------------------------------
__global__ __launch_bounds__(1024) void detect_zero_kernel(
    const uint4* __restrict__ fgq, unsigned int* wsu, float* wsf) {
  uint4 a = fgq[threadIdx.x];
  uint4 b = fgq[threadIdx.x + 1024];
  uint4 c = fgq[threadIdx.x + 2048];
  uint4 d = fgq[threadIdx.x + 3072];
  unsigned int acc = (a.x | a.y | a.z | a.w) | (b.x | b.y | b.z | b.w) |
                     (c.x | c.y | c.z | c.w) | (d.x | d.y | d.z | d.w);
#pragma unroll
  for (int o = 32; o >= 1; o >>= 1) acc |= __shfl_xor(acc, o);
  __shared__ unsigned int sm[16];
  const int wid = threadIdx.x >> 6;
  if ((threadIdx.x & 63) == 0) sm[wid] = acc;
  __syncthreads();
  if (threadIdx.x == 0) {
    unsigned int o = 0;
#pragma unroll
    for (int i = 0; i < 16; ++i) o |= sm[i];
    unsigned int flag;
    if (o == 0x3F800000u) flag = 2u;        // all words are 0.0f / 1.0f
    else if ((o & ~1u) != 0u) flag = 1u;    // bits beyond LSB -> packed bytes
    else flag = 0u;                          // 0/1 int32 words
    wsu[2] = flag;
    wsf[0] = 0.f;
    wsf[1] = 0.f;
  }
}

// ---------------------------------------------------------------------------
// Kernel 2: per-element loss contributions, block-reduced, atomically added.
// One thread per (b,l). Clip polygon lives in LDS (transposed layout:
// bank = tid%32 -> conflict-free) so NOTHING is runtime-indexed in scratch.
// ---------------------------------------------------------------------------
__global__ __launch_bounds__(256) void loss_kernel(
    const float* __restrict__ pred_dist,
    const float* __restrict__ pred_bboxes,
    const float* __restrict__ pred_angles,
    const float* __restrict__ anchor_points,
    const float* __restrict__ target_bboxes,
    const float* __restrict__ target_angles,
    const float* __restrict__ target_scores,
    const void* __restrict__ fgp,
    const unsigned int* __restrict__ wsu,
    float* __restrict__ wsf) {
  const int tid = threadIdx.x;
  const int idx = blockIdx.x * 256 + tid;  // grid sized exactly to NN
  float ci = 0.f, cd = 0.f;

  // sb[buf][coord][slot][tid] : LDS word index = slot*256 + tid
  //  -> bank = tid % 32 regardless of (divergent) slot index: conflict-free.
  __shared__ float sb[2][2][8][256];  // 32 KB

  const unsigned int flag = wsu[2];
  bool fg;
  if (flag == 2u)      fg = ((const float*)fgp)[idx] != 0.f;
  else if (flag == 1u) fg = ((const unsigned char*)fgp)[idx] != 0;
  else                 fg = ((const int*)fgp)[idx] != 0;

  if (fg) {
    const int l = idx % LL;
    const float4 pb = ((const float4*)pred_bboxes)[idx];
    const float4 tb = ((const float4*)target_bboxes)[idx];
    const float kDeg2Rad = 3.14159265358979323846f / 180.f;
    const float pa = pred_angles[idx] * kDeg2Rad;
    const float ta = target_angles[idx] * kDeg2Rad;

    // --- corners of both boxes (CCW) ---
    const float cp = cosf(pa), sp = sinf(pa);
    const float ct = cosf(ta), st = sinf(ta);
    const float txs[4] = {0.5f, -0.5f, -0.5f, 0.5f};
    const float tys[4] = {0.5f, 0.5f, -0.5f, -0.5f};
    float c1x[4], c1y[4], c2x[4], c2y[4];
#pragma unroll
    for (int k = 0; k < 4; ++k) {
      float cx = txs[k] * pb.z, cy = tys[k] * pb.w;
      c1x[k] = cx * cp - cy * sp + pb.x;
      c1y[k] = cx * sp + cy * cp + pb.y;
      cx = txs[k] * tb.z; cy = tys[k] * tb.w;
      c2x[k] = cx * ct - cy * st + tb.x;
      c2y[k] = cx * st + cy * ct + tb.y;
    }

    // --- Sutherland-Hodgman: clip box1 by box2's 4 half-planes ---
    int n, cur = 0;
    {
      // plane 0: input is c1 in registers (all indices compile-time)
      const float rx = c2x[0], ry = c2y[0];
      const float ex = c2x[1] - rx, ey = c2y[1] - ry;
      float dd[4];
#pragma unroll
      for (int k = 0; k < 4; ++k)
        dd[k] = ex * (c1y[k] - ry) - ey * (c1x[k] - rx);
      int m = 0;
#pragma unroll
      for (int i = 0; i < 4; ++i) {
        const int ip = (i + 1) & 3;
        const bool in0 = dd[i] >= 0.f, in1 = dd[ip] >= 0.f;
        if (in0) {
          sb[0][0][m][tid] = c1x[i];
          sb[0][1][m][tid] = c1y[i];
          ++m;
        }
        if (in0 != in1) {
          const float t = dd[i] / (dd[i] - dd[ip]);
          sb[0][0][m][tid] = c1x[i] + t * (c1x[ip] - c1x[i]);
          sb[0][1][m][tid] = c1y[i] + t * (c1y[ip] - c1y[i]);
          ++m;
        }
      }
      n = m;
    }

    // planes 1..3: LDS ping-pong; rx/ry/ex/ey passed with compile-time
    // indices into c2 so c2 stays in registers.
    auto clip_plane = [&](float rx, float ry, float ex, float ey) {
      if (n == 0) return;
      int m = 0;
      float x0 = sb[cur][0][0][tid], y0 = sb[cur][1][0][tid];
      float d0 = ex * (y0 - ry) - ey * (x0 - rx);
      const float xf = x0, yf = y0, df = d0;
      for (int i = 0; i < n; ++i) {
        float x1, y1, d1;
        if (i + 1 == n) {
          x1 = xf; y1 = yf; d1 = df;
        } else {
          x1 = sb[cur][0][i + 1][tid];
          y1 = sb[cur][1][i + 1][tid];
          d1 = ex * (y1 - ry) - ey * (x1 - rx);
        }
        const bool in0 = d0 >= 0.f, in1 = d1 >= 0.f;
        if (in0) {
          sb[cur ^ 1][0][m][tid] = x0;
          sb[cur ^ 1][1][m][tid] = y0;
          ++m;
        }
        if (in0 != in1) {
          const float t = d0 / (d0 - d1);
          sb[cur ^ 1][0][m][tid] = x0 + t * (x1 - x0);
          sb[cur ^ 1][1][m][tid] = y0 + t * (y1 - y0);
          ++m;
        }
        x0 = x1; y0 = y1; d0 = d1;
      }
      cur ^= 1;
      n = m;
    };
    clip_plane(c2x[1], c2y[1], c2x[2] - c2x[1], c2y[2] - c2y[1]);
    clip_plane(c2x[2], c2y[2], c2x[3] - c2x[2], c2y[3] - c2y[2]);
    clip_plane(c2x[3], c2y[3], c2x[0] - c2x[3], c2y[0] - c2y[3]);

    // --- shoelace over surviving polygon ---
    float a2s = 0.f;
    if (n >= 3) {
      const float x0f = sb[cur][0][0][tid], y0f = sb[cur][1][0][tid];
      float xp = x0f, yp = y0f;
      for (int i = 1; i < n; ++i) {
        const float xi = sb[cur][0][i][tid], yi = sb[cur][1][i][tid];
        a2s += xp * yi - xi * yp;
        xp = xi; yp = yi;
      }
      a2s += xp * y0f - x0f * yp;
    }
    const float inter = 0.5f * fabsf(a2s);
    const float a1 = pb.z * pb.w, a2 = tb.z * tb.w;
    const float iou = fmaxf(inter / (a1 + a2 - inter + 1e-8f), 1e-6f);
    const float iou_loss = 1.f - iou;

    // --- bbox_weight = sum over 80 target scores ---
    const float4* sp4 = (const float4*)(target_scores + (size_t)idx * NCLS);
    float bw = 0.f;
#pragma unroll
    for (int k = 0; k < NCLS / 4; ++k) {
      const float4 v = sp4[k];
      bw += (v.x + v.y) + (v.z + v.w);
    }

    // --- DFL ---
    const float2 anc = ((const float2*)anchor_points)[l];
    float dists[4];
    dists[0] = fminf(fmaxf(anc.x - tb.x, 0.f), 15.99f);
    dists[1] = fminf(fmaxf(anc.y - tb.y, 0.f), 15.99f);
    dists[2] = fminf(fmaxf(tb.z - anc.x, 0.f), 15.99f);
    dists[3] = fminf(fmaxf(tb.w - anc.y, 0.f), 15.99f);
    const float* dr = pred_dist + (size_t)idx * 68;
    const float kLog2e = 1.4426950408889634f;
    const float kLn2 = 0.6931471805599453f;
    float dfl = 0.f;
#pragma unroll
    for (int s = 0; s < 4; ++s) {
      const float* row = dr + s * 17;
      float vv[17];
#pragma unroll
      for (int k = 0; k < 17; ++k) vv[k] = row[k];
      float mx = vv[0];
#pragma unroll
      for (int k = 1; k < 17; ++k) mx = fmaxf(mx, vv[k]);
      float se = 0.f;
#pragma unroll
      for (int k = 0; k < 17; ++k) se += exp2f((vv[k] - mx) * kLog2e);
      const float lz = mx + log2f(se) * kLn2;
      const float t = dists[s];
      int tl = (int)t;
      tl = tl < 0 ? 0 : (tl > RMAX - 1 ? RMAX - 1 : tl);
      const float wl = (float)(tl + 1) - t;
      const float wr = 1.f - wl;
      // dynamic index: re-read from global (L1 hit) to avoid scratch
      dfl -= (row[tl] - lz) * wl + (row[tl + 1] - lz) * wr;
    }
    dfl *= 0.25f;

    ci = iou_loss * bw;
    cd = dfl * bw;
  }

  // --- block reduction: wave shfl + LDS across 4 waves + 2 atomics ---
#pragma unroll
  for (int o = 32; o >= 1; o >>= 1) {
    ci += __shfl_xor(ci, o);
    cd += __shfl_xor(cd, o);
  }
  __shared__ float si[4], sd[4];
  const int wid = tid >> 6;
  if ((tid & 63) == 0) { si[wid] = ci; sd[wid] = cd; }
  __syncthreads();
  if (tid == 0) {
    atomicAdd(&wsf[0], (si[0] + si[1]) + (si[2] + si[3]));
    atomicAdd(&wsf[1], (sd[0] + sd[1]) + (sd[2] + sd[3]));
  }
}

// ---------------------------------------------------------------------------
// Kernel 3: finalize
// ---------------------------------------------------------------------------
__global__ void finalize_kernel(const float* __restrict__ wsf,
                                const float* __restrict__ tss_p,
                                float* __restrict__ out) {
  const float tss = tss_p[0];
  const float denom = (tss == 0.f) ? 1.f : tss;
  out[0] = wsf[0] / denom;
  out[1] = wsf[1] / denom;
}

extern "C" void kernel_launch(void* const* d_in, const int* in_sizes, int n_in,
                              void* d_out, int out_size, void* d_ws, size_t ws_size,
                              hipStream_t stream) {
  const float* pred_dist      = (const float*)d_in[0];
  const float* pred_bboxes    = (const float*)d_in[1];
  const float* pred_angles    = (const float*)d_in[2];
  const float* anchor_points  = (const float*)d_in[3];
  const float* target_bboxes  = (const float*)d_in[4];
  const float* target_angles  = (const float*)d_in[5];
  const float* target_scores  = (const float*)d_in[6];
  const float* tss            = (const float*)d_in[7];
  const void*  fgp            = d_in[8];

  float* wsf = (float*)d_ws;
  unsigned int* wsu = (unsigned int*)d_ws;
  float* out = (float*)d_out;

  detect_zero_kernel<<<1, 1024, 0, stream>>>((const uint4*)fgp, wsu, wsf);
  loss_kernel<<<NN / 256, 256, 0, stream>>>(pred_dist, pred_bboxes, pred_angles,
                                            anchor_points, target_bboxes,
                                            target_angles, target_scores, fgp,
                                            wsu, wsf);
  finalize_kernel<<<1, 1, 0, stream>>>(wsf, tss, out);
}

// Round 3
// 22.404 us; speedup vs baseline: 1.8147x; 1.5531x over previous
//
#include <hip/hip_runtime.h>
#include <math.h>

#define NCLS 80
#define LL 21504
#define NNELEM 172032   // 8*21504
#define EPB 512         // elements per block
#define NB 336          // NNELEM / EPB

// ---------------------------------------------------------------------------
// Green's-theorem convex-quad intersection: each edge A->B of one quad is
// clipped (Cyrus-Beck) against the 4 half-planes of the other; the clipped
// piece contributes cross(P(t0), P(t1)). Sum over all 8 edges = 2*Area.
// STRICT=true rejects edges lying exactly ON a clip plane (avoids double
// count when boundaries are collinear). Fully branch-free, register-only.
// ---------------------------------------------------------------------------
template <bool STRICT>
__device__ __forceinline__ float clip_piece(float Ax, float Ay, float Bx, float By,
                                            const float (&nx)[4], const float (&ny)[4],
                                            const float (&off)[4]) {
  const float Dx = Bx - Ax, Dy = By - Ay;
  float t0 = 0.f, t1 = 1.f;
  bool rej = false;
#pragma unroll
  for (int k = 0; k < 4; ++k) {
    const float den = nx[k] * Dx + ny[k] * Dy;
    const float num = nx[k] * Ax + ny[k] * Ay - off[k];
    const float tt = -num / den;
    if (den > 0.f)      t0 = fmaxf(t0, tt);
    else if (den < 0.f) t1 = fminf(t1, tt);
    else                rej = rej || (STRICT ? (num <= 0.f) : (num < 0.f));
  }
  const float X0 = fmaf(t0, Dx, Ax), Y0 = fmaf(t0, Dy, Ay);
  const float X1 = fmaf(t1, Dx, Ax), Y1 = fmaf(t1, Dy, Ay);
  return (!rej && (t0 < t1)) ? (X0 * Y1 - X1 * Y0) : 0.f;
}

__device__ __forceinline__ void heavy_elem(
    int idx,
    const float* __restrict__ pred_dist,
    const float* __restrict__ pred_bboxes,
    const float* __restrict__ pred_angles,
    const float* __restrict__ anchor_points,
    const float* __restrict__ target_bboxes,
    const float* __restrict__ target_angles,
    const float* __restrict__ target_scores,
    float& ci, float& cd) {
  const int l = idx % LL;
  const float4 pb = ((const float4*)pred_bboxes)[idx];
  const float4 tb = ((const float4*)target_bboxes)[idx];
  const float kD2R = 0.017453292519943295f;
  float sp, cp, st, ct;
  __sincosf(pred_angles[idx] * kD2R, &sp, &cp);
  __sincosf(target_angles[idx] * kD2R, &st, &ct);

  // corners (CCW), frame centered on pred box center for fp accuracy
  const float tx[4] = {0.5f, -0.5f, -0.5f, 0.5f};
  const float ty[4] = {0.5f, 0.5f, -0.5f, -0.5f};
  const float qcx = tb.x - pb.x, qcy = tb.y - pb.y;
  float pxx[4], pyy[4], qxx[4], qyy[4];
#pragma unroll
  for (int k = 0; k < 4; ++k) {
    float lx = tx[k] * pb.z, ly = ty[k] * pb.w;
    pxx[k] = lx * cp - ly * sp;
    pyy[k] = lx * sp + ly * cp;
    lx = tx[k] * tb.z; ly = ty[k] * tb.w;
    qxx[k] = lx * ct - ly * st + qcx;
    qyy[k] = lx * st + ly * ct + qcy;
  }
  // inward half-plane normals: n = (-ey, ex), f(X) = n.X - off >= 0 inside
  float pnx[4], pny[4], pof[4], qnx[4], qny[4], qof[4];
#pragma unroll
  for (int k = 0; k < 4; ++k) {
    const int kp = (k + 1) & 3;
    pnx[k] = pyy[k] - pyy[kp]; pny[k] = pxx[kp] - pxx[k];
    pof[k] = pnx[k] * pxx[k] + pny[k] * pyy[k];
    qnx[k] = qyy[k] - qyy[kp]; qny[k] = qxx[kp] - qxx[k];
    qof[k] = qnx[k] * qxx[k] + qny[k] * qyy[k];
  }
  float s2 = 0.f;
#pragma unroll
  for (int i = 0; i < 4; ++i) {
    const int ip = (i + 1) & 3;
    s2 += clip_piece<false>(pxx[i], pyy[i], pxx[ip], pyy[ip], qnx, qny, qof);
  }
#pragma unroll
  for (int i = 0; i < 4; ++i) {
    const int ip = (i + 1) & 3;
    s2 += clip_piece<true>(qxx[i], qyy[i], qxx[ip], qyy[ip], pnx, pny, pof);
  }
  const float inter = 0.5f * fabsf(s2);
  const float a1 = pb.z * pb.w, a2 = tb.z * tb.w;
  const float iou = fmaxf(inter / (a1 + a2 - inter + 1e-8f), 1e-6f);
  const float iou_loss = 1.f - iou;

  // bbox_weight = sum of 80 target scores
  const float4* sp4 = (const float4*)(target_scores + (size_t)idx * NCLS);
  float bw = 0.f;
#pragma unroll
  for (int k = 0; k < NCLS / 4; ++k) {
    const float4 v = sp4[k];
    bw += (v.x + v.y) + (v.z + v.w);
  }

  // DFL
  const float2 anc = ((const float2*)anchor_points)[l];
  float dists[4];
  dists[0] = fminf(fmaxf(anc.x - tb.x, 0.f), 15.99f);
  dists[1] = fminf(fmaxf(anc.y - tb.y, 0.f), 15.99f);
  dists[2] = fminf(fmaxf(tb.z - anc.x, 0.f), 15.99f);
  dists[3] = fminf(fmaxf(tb.w - anc.y, 0.f), 15.99f);
  const float* dr = pred_dist + (size_t)idx * 68;  // rows are 16B-aligned (272B)
  float4 v4[17];
#pragma unroll
  for (int k = 0; k < 17; ++k) v4[k] = ((const float4*)dr)[k];
  float vv[68];
#pragma unroll
  for (int k = 0; k < 17; ++k) {
    vv[4 * k] = v4[k].x; vv[4 * k + 1] = v4[k].y;
    vv[4 * k + 2] = v4[k].z; vv[4 * k + 3] = v4[k].w;
  }
  const float kLog2e = 1.4426950408889634f;
  const float kLn2 = 0.6931471805599453f;
  float dfl = 0.f;
#pragma unroll
  for (int s = 0; s < 4; ++s) {
    float mx = vv[17 * s];
#pragma unroll
    for (int k = 1; k < 17; ++k) mx = fmaxf(mx, vv[17 * s + k]);
    float se = 0.f;
#pragma unroll
    for (int k = 0; k < 17; ++k) se += exp2f((vv[17 * s + k] - mx) * kLog2e);
    const float lz = mx + log2f(se) * kLn2;
    const float t = dists[s];
    int tl = (int)t;
    tl = tl < 0 ? 0 : (tl > 15 ? 15 : tl);
    const float wl = (float)(tl + 1) - t;
    const float wr = 1.f - wl;
    const float* row = dr + s * 17;
    // dynamic index: re-read via L1 (lines are hot) to avoid scratch
    dfl -= (row[tl] - lz) * wl + (row[tl + 1] - lz) * wr;
  }
  dfl *= 0.25f;

  ci = fmaf(iou_loss, bw, ci);
  cd = fmaf(dfl, bw, cd);
}

// ---------------------------------------------------------------------------
// Main kernel: one wave per 512 elements. Detect mask layout from own data,
// ballot-compact fg indices into LDS, process densely, write partial sums.
// ---------------------------------------------------------------------------
__global__ __launch_bounds__(64) void main_kernel(
    const float* __restrict__ pred_dist,
    const float* __restrict__ pred_bboxes,
    const float* __restrict__ pred_angles,
    const float* __restrict__ anchor_points,
    const float* __restrict__ target_bboxes,
    const float* __restrict__ target_angles,
    const float* __restrict__ target_scores,
    const void* __restrict__ fgp,
    float2* __restrict__ partials) {
  const int blk = blockIdx.x;
  const int lane = threadIdx.x;
  const int base = blk * EPB;

  // Byte-region of this block's elements: words [blk*128, +128) -> uint2/lane.
  // In-bounds under every layout (byte buffer is exactly 43008 words).
  const uint2 dw = ((const uint2*)fgp)[blk * 64 + lane];
  unsigned int x = dw.x | dw.y;
#pragma unroll
  for (int o = 32; o >= 1; o >>= 1) x |= __shfl_xor(x, o);
  // bytes-layout iff every byte of the OR is 0/1 and something beyond LSB set
  const bool isByte = ((x & ~0x01010101u) == 0u) && (x > 1u);

  unsigned int bits = 0;
  if (isByte) {
    // dw already holds this lane's 8 mask bytes
#pragma unroll
    for (int b = 0; b < 4; ++b) {
      bits |= (((dw.x >> (8 * b)) & 0xFFu) != 0u ? 1u : 0u) << b;
      bits |= (((dw.y >> (8 * b)) & 0xFFu) != 0u ? 1u : 0u) << (4 + b);
    }
  } else {
    // 4-byte layout (int32 or float32: !=0 is correct for both)
    const uint4 w0 = ((const uint4*)fgp)[blk * 128 + 2 * lane];
    const uint4 w1 = ((const uint4*)fgp)[blk * 128 + 2 * lane + 1];
    bits = (unsigned)(w0.x != 0) | ((unsigned)(w0.y != 0) << 1) |
           ((unsigned)(w0.z != 0) << 2) | ((unsigned)(w0.w != 0) << 3) |
           ((unsigned)(w1.x != 0) << 4) | ((unsigned)(w1.y != 0) << 5) |
           ((unsigned)(w1.z != 0) << 6) | ((unsigned)(w1.w != 0) << 7);
  }

  const int cnt = __popc(bits);
  int pre = cnt;  // inclusive wave prefix
#pragma unroll
  for (int o = 1; o < 64; o <<= 1) {
    const int v = __shfl_up(pre, o);
    if (lane >= o) pre += v;
  }
  const int total = __shfl(pre, 63);
  int wo = pre - cnt;
  __shared__ unsigned short sl[EPB];
#pragma unroll
  for (int b = 0; b < 8; ++b) {
    if (bits & (1u << b)) { sl[wo] = (unsigned short)(lane * 8 + b); ++wo; }
  }
  // single wave: LDS write->read ordering handled by lgkmcnt, no barrier

  float ci = 0.f, cd = 0.f;
  for (int j = lane; j < total; j += 64) {
    heavy_elem(base + (int)sl[j], pred_dist, pred_bboxes, pred_angles,
               anchor_points, target_bboxes, target_angles, target_scores,
               ci, cd);
  }
#pragma unroll
  for (int o = 32; o >= 1; o >>= 1) {
    ci += __shfl_xor(ci, o);
    cd += __shfl_xor(cd, o);
  }
  if (lane == 0) partials[blk] = make_float2(ci, cd);
}

// ---------------------------------------------------------------------------
// Finalize: sum 336 partials, divide by target_scores_sum.
// ---------------------------------------------------------------------------
__global__ __launch_bounds__(384) void final_kernel(
    const float2* __restrict__ partials,
    const float* __restrict__ tss_p,
    float* __restrict__ out) {
  const int t = threadIdx.x;
  float a = 0.f, b = 0.f;
  if (t < NB) { const float2 p = partials[t]; a = p.x; b = p.y; }
#pragma unroll
  for (int o = 32; o >= 1; o >>= 1) {
    a += __shfl_xor(a, o);
    b += __shfl_xor(b, o);
  }
  __shared__ float sa[6], sb[6];
  const int w = t >> 6;
  if ((t & 63) == 0) { sa[w] = a; sb[w] = b; }
  __syncthreads();
  if (t == 0) {
    float s0 = 0.f, s1 = 0.f;
#pragma unroll
    for (int i = 0; i < 6; ++i) { s0 += sa[i]; s1 += sb[i]; }
    const float ts = tss_p[0];
    const float denom = (ts == 0.f) ? 1.f : ts;
    out[0] = s0 / denom;
    out[1] = s1 / denom;
  }
}

extern "C" void kernel_launch(void* const* d_in, const int* in_sizes, int n_in,
                              void* d_out, int out_size, void* d_ws, size_t ws_size,
                              hipStream_t stream) {
  const float* pred_dist      = (const float*)d_in[0];
  const float* pred_bboxes    = (const float*)d_in[1];
  const float* pred_angles    = (const float*)d_in[2];
  const float* anchor_points  = (const float*)d_in[3];
  const float* target_bboxes  = (const float*)d_in[4];
  const float* target_angles  = (const float*)d_in[5];
  const float* target_scores  = (const float*)d_in[6];
  const float* tss            = (const float*)d_in[7];
  const void*  fgp            = d_in[8];

  float2* partials = (float2*)d_ws;
  float* out = (float*)d_out;

  main_kernel<<<NB, 64, 0, stream>>>(pred_dist, pred_bboxes, pred_angles,
                                     anchor_points, target_bboxes, target_angles,
                                     target_scores, fgp, partials);
  final_kernel<<<1, 384, 0, stream>>>(partials, tss, out);
}

// Round 4
// 18.608 us; speedup vs baseline: 2.1849x; 1.2040x over previous
//
#include <hip/hip_runtime.h>
#include <math.h>

#define NCLS 80
#define LL 21504
#define NNELEM 172032   // 8*21504
#define EPB 128         // elements per block
#define NB 1344         // NNELEM / EPB

// ---------------------------------------------------------------------------
// Green's-theorem convex-quad intersection: each edge A->B of one quad is
// clipped (Cyrus-Beck) against the 4 half-planes of the other; the clipped
// piece contributes cross(P(t0), P(t1)). Sum over all 8 edges = 2*Area.
// STRICT=true rejects edges lying exactly ON a clip plane (avoids double
// count when boundaries are collinear). Fully branch-free, register-only.
// ---------------------------------------------------------------------------
template <bool STRICT>
__device__ __forceinline__ float clip_piece(float Ax, float Ay, float Bx, float By,
                                            const float (&nx)[4], const float (&ny)[4],
                                            const float (&off)[4]) {
  const float Dx = Bx - Ax, Dy = By - Ay;
  float t0 = 0.f, t1 = 1.f;
  bool rej = false;
#pragma unroll
  for (int k = 0; k < 4; ++k) {
    const float den = nx[k] * Dx + ny[k] * Dy;
    const float num = nx[k] * Ax + ny[k] * Ay - off[k];
    const float tt = -num / den;
    if (den > 0.f)      t0 = fmaxf(t0, tt);
    else if (den < 0.f) t1 = fminf(t1, tt);
    else                rej = rej || (STRICT ? (num <= 0.f) : (num < 0.f));
  }
  const float X0 = fmaf(t0, Dx, Ax), Y0 = fmaf(t0, Dy, Ay);
  const float X1 = fmaf(t1, Dx, Ax), Y1 = fmaf(t1, Dy, Ay);
  return (!rej && (t0 < t1)) ? (X0 * Y1 - X1 * Y0) : 0.f;
}

__device__ __forceinline__ void heavy_elem(
    int idx,
    const float* __restrict__ pred_dist,
    const float* __restrict__ pred_bboxes,
    const float* __restrict__ pred_angles,
    const float* __restrict__ anchor_points,
    const float* __restrict__ target_bboxes,
    const float* __restrict__ target_angles,
    const float* __restrict__ target_scores,
    float& ci, float& cd) {
  const int l = idx % LL;
  const float4 pb = ((const float4*)pred_bboxes)[idx];
  const float4 tb = ((const float4*)target_bboxes)[idx];
  const float kD2R = 0.017453292519943295f;
  float sp, cp, st, ct;
  __sincosf(pred_angles[idx] * kD2R, &sp, &cp);
  __sincosf(target_angles[idx] * kD2R, &st, &ct);

  // corners (CCW), frame centered on pred box center for fp accuracy
  const float tx[4] = {0.5f, -0.5f, -0.5f, 0.5f};
  const float ty[4] = {0.5f, 0.5f, -0.5f, -0.5f};
  const float qcx = tb.x - pb.x, qcy = tb.y - pb.y;
  float pxx[4], pyy[4], qxx[4], qyy[4];
#pragma unroll
  for (int k = 0; k < 4; ++k) {
    float lx = tx[k] * pb.z, ly = ty[k] * pb.w;
    pxx[k] = lx * cp - ly * sp;
    pyy[k] = lx * sp + ly * cp;
    lx = tx[k] * tb.z; ly = ty[k] * tb.w;
    qxx[k] = lx * ct - ly * st + qcx;
    qyy[k] = lx * st + ly * ct + qcy;
  }
  // inward half-plane normals: n = (-ey, ex), f(X) = n.X - off >= 0 inside
  float pnx[4], pny[4], pof[4], qnx[4], qny[4], qof[4];
#pragma unroll
  for (int k = 0; k < 4; ++k) {
    const int kp = (k + 1) & 3;
    pnx[k] = pyy[k] - pyy[kp]; pny[k] = pxx[kp] - pxx[k];
    pof[k] = pnx[k] * pxx[k] + pny[k] * pyy[k];
    qnx[k] = qyy[k] - qyy[kp]; qny[k] = qxx[kp] - qxx[k];
    qof[k] = qnx[k] * qxx[k] + qny[k] * qyy[k];
  }
  float s2 = 0.f;
#pragma unroll
  for (int i = 0; i < 4; ++i) {
    const int ip = (i + 1) & 3;
    s2 += clip_piece<false>(pxx[i], pyy[i], pxx[ip], pyy[ip], qnx, qny, qof);
  }
#pragma unroll
  for (int i = 0; i < 4; ++i) {
    const int ip = (i + 1) & 3;
    s2 += clip_piece<true>(qxx[i], qyy[i], qxx[ip], qyy[ip], pnx, pny, pof);
  }
  const float inter = 0.5f * fabsf(s2);
  const float a1 = pb.z * pb.w, a2 = tb.z * tb.w;
  const float iou = fmaxf(inter / (a1 + a2 - inter + 1e-8f), 1e-6f);
  const float iou_loss = 1.f - iou;

  // bbox_weight = sum of 80 target scores
  const float4* sp4 = (const float4*)(target_scores + (size_t)idx * NCLS);
  float bw = 0.f;
#pragma unroll
  for (int k = 0; k < NCLS / 4; ++k) {
    const float4 v = sp4[k];
    bw += (v.x + v.y) + (v.z + v.w);
  }

  // DFL
  const float2 anc = ((const float2*)anchor_points)[l];
  float dists[4];
  dists[0] = fminf(fmaxf(anc.x - tb.x, 0.f), 15.99f);
  dists[1] = fminf(fmaxf(anc.y - tb.y, 0.f), 15.99f);
  dists[2] = fminf(fmaxf(tb.z - anc.x, 0.f), 15.99f);
  dists[3] = fminf(fmaxf(tb.w - anc.y, 0.f), 15.99f);
  const float* dr = pred_dist + (size_t)idx * 68;  // rows are 16B-aligned (272B)
  float4 v4[17];
#pragma unroll
  for (int k = 0; k < 17; ++k) v4[k] = ((const float4*)dr)[k];
  float vv[68];
#pragma unroll
  for (int k = 0; k < 17; ++k) {
    vv[4 * k] = v4[k].x; vv[4 * k + 1] = v4[k].y;
    vv[4 * k + 2] = v4[k].z; vv[4 * k + 3] = v4[k].w;
  }
  const float kLog2e = 1.4426950408889634f;
  const float kLn2 = 0.6931471805599453f;
  float dfl = 0.f;
#pragma unroll
  for (int s = 0; s < 4; ++s) {
    float mx = vv[17 * s];
#pragma unroll
    for (int k = 1; k < 17; ++k) mx = fmaxf(mx, vv[17 * s + k]);
    float se = 0.f;
#pragma unroll
    for (int k = 0; k < 17; ++k) se += exp2f((vv[17 * s + k] - mx) * kLog2e);
    const float lz = mx + log2f(se) * kLn2;
    const float t = dists[s];
    int tl = (int)t;
    tl = tl < 0 ? 0 : (tl > 15 ? 15 : tl);
    const float wl = (float)(tl + 1) - t;
    const float wr = 1.f - wl;
    const float* row = dr + s * 17;
    // dynamic index: re-read via L1 (lines are hot) to avoid scratch
    dfl -= (row[tl] - lz) * wl + (row[tl + 1] - lz) * wr;
  }
  dfl *= 0.25f;

  ci = fmaf(iou_loss, bw, ci);
  cd = fmaf(dfl, bw, cd);
}

// ---------------------------------------------------------------------------
// Main kernel: one wave per 128 elements (1344 waves -> ~5 waves/CU for
// latency hiding). Mask layout detected from a FIXED 256-byte window (same
// for every block, L2-hot, globally safe); own region then read in the
// detected layout. Ballot-compact fg indices into LDS, process densely.
// ---------------------------------------------------------------------------
__global__ __launch_bounds__(64) void main_kernel(
    const float* __restrict__ pred_dist,
    const float* __restrict__ pred_bboxes,
    const float* __restrict__ pred_angles,
    const float* __restrict__ anchor_points,
    const float* __restrict__ target_bboxes,
    const float* __restrict__ target_angles,
    const float* __restrict__ target_scores,
    const void* __restrict__ fgp,
    float2* __restrict__ partials) {
  const int blk = blockIdx.x;
  const int lane = threadIdx.x;
  const int base = blk * EPB;

  // ---- layout detection from fixed window: bytes [0, 256) ----
  unsigned int x = ((const unsigned int*)fgp)[lane];
#pragma unroll
  for (int o = 32; o >= 1; o >>= 1) x |= __shfl_xor(x, o);
  // byte-layout iff OR has only 0x01 bytes and a set bit beyond bit 0
  const bool isByte = ((x & ~0x01010101u) == 0u) && (x > 1u);

  // ---- own-region mask read: 2 elements per lane ----
  unsigned int bits;
  if (isByte) {
    const unsigned short v = ((const unsigned short*)fgp)[blk * 64 + lane];
    bits = ((v & 0xFFu) ? 1u : 0u) | ((v >> 8) ? 2u : 0u);
  } else {
    // 4-byte layout (int32 or float32: !=0 correct for both)
    const uint2 w = ((const uint2*)fgp)[blk * 64 + lane];
    bits = (w.x ? 1u : 0u) | (w.y ? 2u : 0u);
  }

  const int cnt = __popc(bits);
  int pre = cnt;  // inclusive wave prefix
#pragma unroll
  for (int o = 1; o < 64; o <<= 1) {
    const int v = __shfl_up(pre, o);
    if (lane >= o) pre += v;
  }
  const int total = __shfl(pre, 63);
  int wo = pre - cnt;
  __shared__ unsigned short sl[EPB];
  if (bits & 1u) { sl[wo] = (unsigned short)(lane * 2); ++wo; }
  if (bits & 2u) { sl[wo] = (unsigned short)(lane * 2 + 1); }
  // single wave: LDS write->read ordering handled by lgkmcnt, no barrier

  float ci = 0.f, cd = 0.f;
  for (int j = lane; j < total; j += 64) {
    heavy_elem(base + (int)sl[j], pred_dist, pred_bboxes, pred_angles,
               anchor_points, target_bboxes, target_angles, target_scores,
               ci, cd);
  }
#pragma unroll
  for (int o = 32; o >= 1; o >>= 1) {
    ci += __shfl_xor(ci, o);
    cd += __shfl_xor(cd, o);
  }
  if (lane == 0) partials[blk] = make_float2(ci, cd);
}

// ---------------------------------------------------------------------------
// Finalize: sum 1344 partials, divide by target_scores_sum.
// ---------------------------------------------------------------------------
__global__ __launch_bounds__(512) void final_kernel(
    const float2* __restrict__ partials,
    const float* __restrict__ tss_p,
    float* __restrict__ out) {
  const int t = threadIdx.x;
  float a = 0.f, b = 0.f;
#pragma unroll
  for (int i = 0; i < 3; ++i) {
    const int j = t + i * 512;
    if (j < NB) { const float2 p = partials[j]; a += p.x; b += p.y; }
  }
#pragma unroll
  for (int o = 32; o >= 1; o >>= 1) {
    a += __shfl_xor(a, o);
    b += __shfl_xor(b, o);
  }
  __shared__ float sa[8], sb[8];
  const int w = t >> 6;
  if ((t & 63) == 0) { sa[w] = a; sb[w] = b; }
  __syncthreads();
  if (t == 0) {
    float s0 = 0.f, s1 = 0.f;
#pragma unroll
    for (int i = 0; i < 8; ++i) { s0 += sa[i]; s1 += sb[i]; }
    const float ts = tss_p[0];
    const float denom = (ts == 0.f) ? 1.f : ts;
    out[0] = s0 / denom;
    out[1] = s1 / denom;
  }
}

extern "C" void kernel_launch(void* const* d_in, const int* in_sizes, int n_in,
                              void* d_out, int out_size, void* d_ws, size_t ws_size,
                              hipStream_t stream) {
  const float* pred_dist      = (const float*)d_in[0];
  const float* pred_bboxes    = (const float*)d_in[1];
  const float* pred_angles    = (const float*)d_in[2];
  const float* anchor_points  = (const float*)d_in[3];
  const float* target_bboxes  = (const float*)d_in[4];
  const float* target_angles  = (const float*)d_in[5];
  const float* target_scores  = (const float*)d_in[6];
  const float* tss            = (const float*)d_in[7];
  const void*  fgp            = d_in[8];

  float2* partials = (float2*)d_ws;
  float* out = (float*)d_out;

  main_kernel<<<NB, 64, 0, stream>>>(pred_dist, pred_bboxes, pred_angles,
                                     anchor_points, target_bboxes, target_angles,
                                     target_scores, fgp, partials);
  final_kernel<<<1, 512, 0, stream>>>(partials, tss, out);
}

// Round 5
// 15.859 us; speedup vs baseline: 2.5635x; 1.1733x over previous
//
#include <hip/hip_runtime.h>
#include <math.h>

#define NCLS 80
#define LL 21504
#define NNELEM 172032   // 8*21504
#define EPB 128         // elements per block (one wave per block)
#define NB 1344         // NNELEM / EPB

// ---------------------------------------------------------------------------
// Green's-theorem convex-quad intersection piece: edge A->B clipped
// (Cyrus-Beck) against 4 half-planes; contributes cross(P(t0), P(t1)).
// STRICT=true rejects edges lying exactly ON a clip plane (avoids double
// count when boundaries are collinear). Branch-free, register-only.
// ---------------------------------------------------------------------------
template <bool STRICT>
__device__ __forceinline__ float clip_piece(float Ax, float Ay, float Bx, float By,
                                            const float (&nx)[4], const float (&ny)[4],
                                            const float (&off)[4]) {
  const float Dx = Bx - Ax, Dy = By - Ay;
  float t0 = 0.f, t1 = 1.f;
  bool rej = false;
#pragma unroll
  for (int k = 0; k < 4; ++k) {
    const float den = nx[k] * Dx + ny[k] * Dy;
    const float num = nx[k] * Ax + ny[k] * Ay - off[k];
    const float tt = -num / den;
    if (den > 0.f)      t0 = fmaxf(t0, tt);
    else if (den < 0.f) t1 = fminf(t1, tt);
    else                rej = rej || (STRICT ? (num <= 0.f) : (num < 0.f));
  }
  const float X0 = fmaf(t0, Dx, Ax), Y0 = fmaf(t0, Dy, Ay);
  const float X1 = fmaf(t1, Dx, Ax), Y1 = fmaf(t1, Dy, Ay);
  return (!rej && (t0 < t1)) ? (X0 * Y1 - X1 * Y0) : 0.f;
}

// select arr[i] for runtime i in [0,4) without scratch (3 cndmasks)
__device__ __forceinline__ float sel4(float a0, float a1, float a2, float a3, int i) {
  float r = (i == 1) ? a1 : a0;
  r = (i == 2) ? a2 : r;
  r = (i == 3) ? a3 : r;
  return r;
}

// ---------------------------------------------------------------------------
// One fg element processed cooperatively by a 4-lane team.
// sub in [0,4): lane's role. Work split: clip edge pair (1 P-edge + 1
// Q-edge), one of 4 DFL softmax rows, 20 of 80 score floats. Partials are
// combined with intra-quad shfl_xor butterflies (quads are lane-aligned).
// ---------------------------------------------------------------------------
__device__ __forceinline__ void team_elem(
    int idx, int sub,
    const float* __restrict__ pred_dist,
    const float* __restrict__ pred_bboxes,
    const float* __restrict__ pred_angles,
    const float* __restrict__ anchor_points,
    const float* __restrict__ target_bboxes,
    const float* __restrict__ target_angles,
    const float* __restrict__ target_scores,
    float& ci, float& cd) {
  const int l = idx % LL;
  const float4 pb = ((const float4*)pred_bboxes)[idx];
  const float4 tb = ((const float4*)target_bboxes)[idx];
  const float kD2R = 0.017453292519943295f;
  float sp, cp, st, ct;
  __sincosf(pred_angles[idx] * kD2R, &sp, &cp);
  __sincosf(target_angles[idx] * kD2R, &st, &ct);

  // corners (CCW), frame centered on pred box center (replicated on team)
  const float tx[4] = {0.5f, -0.5f, -0.5f, 0.5f};
  const float ty[4] = {0.5f, 0.5f, -0.5f, -0.5f};
  const float qcx = tb.x - pb.x, qcy = tb.y - pb.y;
  float pxx[4], pyy[4], qxx[4], qyy[4];
#pragma unroll
  for (int k = 0; k < 4; ++k) {
    float lx = tx[k] * pb.z, ly = ty[k] * pb.w;
    pxx[k] = lx * cp - ly * sp;
    pyy[k] = lx * sp + ly * cp;
    lx = tx[k] * tb.z; ly = ty[k] * tb.w;
    qxx[k] = lx * ct - ly * st + qcx;
    qyy[k] = lx * st + ly * ct + qcy;
  }
  // inward half-plane normals (replicated; statically indexed everywhere)
  float pnx[4], pny[4], pof[4], qnx[4], qny[4], qof[4];
#pragma unroll
  for (int k = 0; k < 4; ++k) {
    const int kp = (k + 1) & 3;
    pnx[k] = pyy[k] - pyy[kp]; pny[k] = pxx[kp] - pxx[k];
    pof[k] = pnx[k] * pxx[k] + pny[k] * pyy[k];
    qnx[k] = qyy[k] - qyy[kp]; qny[k] = qxx[kp] - qxx[k];
    qof[k] = qnx[k] * qxx[k] + qny[k] * qyy[k];
  }

  // --- this lane's two clip edges (endpoints via cndmask selects) ---
  const int subp = (sub + 1) & 3;
  const float pax = sel4(pxx[0], pxx[1], pxx[2], pxx[3], sub);
  const float pay = sel4(pyy[0], pyy[1], pyy[2], pyy[3], sub);
  const float pbx = sel4(pxx[0], pxx[1], pxx[2], pxx[3], subp);
  const float pby = sel4(pyy[0], pyy[1], pyy[2], pyy[3], subp);
  const float qax = sel4(qxx[0], qxx[1], qxx[2], qxx[3], sub);
  const float qay = sel4(qyy[0], qyy[1], qyy[2], qyy[3], sub);
  const float qbx = sel4(qxx[0], qxx[1], qxx[2], qxx[3], subp);
  const float qby = sel4(qyy[0], qyy[1], qyy[2], qyy[3], subp);
  float s2 = clip_piece<false>(pax, pay, pbx, pby, qnx, qny, qof) +
             clip_piece<true>(qax, qay, qbx, qby, pnx, pny, pof);
  s2 += __shfl_xor(s2, 1);
  s2 += __shfl_xor(s2, 2);

  const float inter = 0.5f * fabsf(s2);
  const float a1 = pb.z * pb.w, a2 = tb.z * tb.w;
  const float iou = fmaxf(inter / (a1 + a2 - inter + 1e-8f), 1e-6f);
  const float iou_loss = 1.f - iou;

  // --- bbox_weight: 20 of 80 scores per lane ---
  const float4* sp4 = (const float4*)(target_scores + (size_t)idx * NCLS) + sub * 5;
  float bw = 0.f;
#pragma unroll
  for (int k = 0; k < 5; ++k) {
    const float4 v = sp4[k];
    bw += (v.x + v.y) + (v.z + v.w);
  }
  bw += __shfl_xor(bw, 1);
  bw += __shfl_xor(bw, 2);

  // --- DFL: row s == sub per lane ---
  const float2 anc = ((const float2*)anchor_points)[l];
  const float d0 = anc.x - tb.x, d1 = anc.y - tb.y;
  const float d2 = tb.z - anc.x, d3 = tb.w - anc.y;
  const float t = fminf(fmaxf(sel4(d0, d1, d2, d3, sub), 0.f), 15.99f);
  const float* row = pred_dist + (size_t)idx * 68 + sub * 17;
  float vv[17];
#pragma unroll
  for (int k = 0; k < 17; ++k) vv[k] = row[k];
  float mx = vv[0];
#pragma unroll
  for (int k = 1; k < 17; ++k) mx = fmaxf(mx, vv[k]);
  const float kLog2e = 1.4426950408889634f;
  const float kLn2 = 0.6931471805599453f;
  float se = 0.f;
#pragma unroll
  for (int k = 0; k < 17; ++k) se += exp2f((vv[k] - mx) * kLog2e);
  const float lz = mx + log2f(se) * kLn2;
  int tl = (int)t;
  tl = tl < 0 ? 0 : (tl > 15 ? 15 : tl);
  const float wl = (float)(tl + 1) - t;
  const float wr = 1.f - wl;
  // register select-chain instead of dependent L1 re-reads
  float vtl = vv[0], vtl1 = vv[1];
#pragma unroll
  for (int k = 1; k < 16; ++k) {
    vtl  = (k == tl) ? vv[k]     : vtl;
    vtl1 = (k == tl) ? vv[k + 1] : vtl1;
  }
  float dfl = -((vtl - lz) * wl + (vtl1 - lz) * wr);
  dfl += __shfl_xor(dfl, 1);
  dfl += __shfl_xor(dfl, 2);
  dfl *= 0.25f;

  if (sub == 0) {
    ci = fmaf(iou_loss, bw, ci);
    cd = fmaf(dfl, bw, cd);
  }
}

// ---------------------------------------------------------------------------
// Main kernel: one wave per 128 elements; ballot-compact fg indices into
// LDS; 16 four-lane teams consume the list (~13 fg -> 1 pass, ~80% lane
// utilization). Mask layout detected from a fixed 256-byte window.
// ---------------------------------------------------------------------------
__global__ __launch_bounds__(64) void main_kernel(
    const float* __restrict__ pred_dist,
    const float* __restrict__ pred_bboxes,
    const float* __restrict__ pred_angles,
    const float* __restrict__ anchor_points,
    const float* __restrict__ target_bboxes,
    const float* __restrict__ target_angles,
    const float* __restrict__ target_scores,
    const void* __restrict__ fgp,
    float2* __restrict__ partials) {
  const int blk = blockIdx.x;
  const int lane = threadIdx.x;
  const int base = blk * EPB;

  // ---- layout detection from fixed window: bytes [0, 256) ----
  unsigned int x = ((const unsigned int*)fgp)[lane];
#pragma unroll
  for (int o = 32; o >= 1; o >>= 1) x |= __shfl_xor(x, o);
  // byte-layout iff OR has only 0x01 bytes and a set bit beyond bit 0
  const bool isByte = ((x & ~0x01010101u) == 0u) && (x > 1u);

  // ---- own-region mask read: 2 elements per lane ----
  unsigned int bits;
  if (isByte) {
    const unsigned short v = ((const unsigned short*)fgp)[blk * 64 + lane];
    bits = ((v & 0xFFu) ? 1u : 0u) | ((v >> 8) ? 2u : 0u);
  } else {
    // 4-byte layout (int32 or float32: !=0 correct for both)
    const uint2 w = ((const uint2*)fgp)[blk * 64 + lane];
    bits = (w.x ? 1u : 0u) | (w.y ? 2u : 0u);
  }

  const int cnt = __popc(bits);
  int pre = cnt;  // inclusive wave prefix
#pragma unroll
  for (int o = 1; o < 64; o <<= 1) {
    const int v = __shfl_up(pre, o);
    if (lane >= o) pre += v;
  }
  const int total = __shfl(pre, 63);
  int wo = pre - cnt;
  __shared__ unsigned short sl[EPB];
  if (bits & 1u) { sl[wo] = (unsigned short)(lane * 2); ++wo; }
  if (bits & 2u) { sl[wo] = (unsigned short)(lane * 2 + 1); }
  // single wave: LDS write->read ordering handled by lgkmcnt, no barrier

  const int team = lane >> 2, sub = lane & 3;
  float ci = 0.f, cd = 0.f;
  for (int j = team; j < total; j += 16) {   // uniform across each quad
    team_elem(base + (int)sl[j], sub, pred_dist, pred_bboxes, pred_angles,
              anchor_points, target_bboxes, target_angles, target_scores,
              ci, cd);
  }
#pragma unroll
  for (int o = 32; o >= 1; o >>= 1) {
    ci += __shfl_xor(ci, o);
    cd += __shfl_xor(cd, o);
  }
  if (lane == 0) partials[blk] = make_float2(ci, cd);
}

// ---------------------------------------------------------------------------
// Finalize: sum 1344 partials, divide by target_scores_sum.
// ---------------------------------------------------------------------------
__global__ __launch_bounds__(512) void final_kernel(
    const float2* __restrict__ partials,
    const float* __restrict__ tss_p,
    float* __restrict__ out) {
  const int t = threadIdx.x;
  float a = 0.f, b = 0.f;
#pragma unroll
  for (int i = 0; i < 3; ++i) {
    const int j = t + i * 512;
    if (j < NB) { const float2 p = partials[j]; a += p.x; b += p.y; }
  }
#pragma unroll
  for (int o = 32; o >= 1; o >>= 1) {
    a += __shfl_xor(a, o);
    b += __shfl_xor(b, o);
  }
  __shared__ float sa[8], sb[8];
  const int w = t >> 6;
  if ((t & 63) == 0) { sa[w] = a; sb[w] = b; }
  __syncthreads();
  if (t == 0) {
    float s0 = 0.f, s1 = 0.f;
#pragma unroll
    for (int i = 0; i < 8; ++i) { s0 += sa[i]; s1 += sb[i]; }
    const float ts = tss_p[0];
    const float denom = (ts == 0.f) ? 1.f : ts;
    out[0] = s0 / denom;
    out[1] = s1 / denom;
  }
}

extern "C" void kernel_launch(void* const* d_in, const int* in_sizes, int n_in,
                              void* d_out, int out_size, void* d_ws, size_t ws_size,
                              hipStream_t stream) {
  const float* pred_dist      = (const float*)d_in[0];
  const float* pred_bboxes    = (const float*)d_in[1];
  const float* pred_angles    = (const float*)d_in[2];
  const float* anchor_points  = (const float*)d_in[3];
  const float* target_bboxes  = (const float*)d_in[4];
  const float* target_angles  = (const float*)d_in[5];
  const float* target_scores  = (const float*)d_in[6];
  const float* tss            = (const float*)d_in[7];
  const void*  fgp            = d_in[8];

  float2* partials = (float2*)d_ws;
  float* out = (float*)d_out;

  main_kernel<<<NB, 64, 0, stream>>>(pred_dist, pred_bboxes, pred_angles,
                                     anchor_points, target_bboxes, target_angles,
                                     target_scores, fgp, partials);
  final_kernel<<<1, 512, 0, stream>>>(partials, tss, out);
}

// Round 7
// 15.645 us; speedup vs baseline: 2.5987x; 1.0137x over previous
//
#include <hip/hip_runtime.h>
#include <math.h>

#define NCLS 80
#define LL 21504
#define NNELEM 172032   // 8*21504
#define EPB 64          // elements per block (one wave, one element per lane)
#define NB 2688         // NNELEM / EPB

// ---------------------------------------------------------------------------
// Green's-theorem convex-quad intersection piece: edge A->B clipped
// (Cyrus-Beck) against 4 half-planes; contributes cross(P(t0), P(t1)).
// STRICT=true rejects edges lying exactly ON a clip plane (avoids double
// count when boundaries are collinear). Branch-free, register-only.
// ---------------------------------------------------------------------------
template <bool STRICT>
__device__ __forceinline__ float clip_piece(float Ax, float Ay, float Bx, float By,
                                            const float (&nx)[4], const float (&ny)[4],
                                            const float (&off)[4]) {
  const float Dx = Bx - Ax, Dy = By - Ay;
  float t0 = 0.f, t1 = 1.f;
  bool rej = false;
#pragma unroll
  for (int k = 0; k < 4; ++k) {
    const float den = nx[k] * Dx + ny[k] * Dy;
    const float num = nx[k] * Ax + ny[k] * Ay - off[k];
    const float tt = -num / den;
    if (den > 0.f)      t0 = fmaxf(t0, tt);
    else if (den < 0.f) t1 = fminf(t1, tt);
    else                rej = rej || (STRICT ? (num <= 0.f) : (num < 0.f));
  }
  const float X0 = fmaf(t0, Dx, Ax), Y0 = fmaf(t0, Dy, Ay);
  const float X1 = fmaf(t1, Dx, Ax), Y1 = fmaf(t1, Dy, Ay);
  return (!rej && (t0 < t1)) ? (X0 * Y1 - X1 * Y0) : 0.f;
}

// select arr[i] for runtime i in [0,4) without scratch (3 cndmasks)
__device__ __forceinline__ float sel4(float a0, float a1, float a2, float a3, int i) {
  float r = (i == 1) ? a1 : a0;
  r = (i == 2) ? a2 : r;
  r = (i == 3) ? a3 : r;
  return r;
}

// position of the j-th (0-based) set bit of m; 6-step popc binary search,
// uniform per 4-lane team (j is team-uniform), ~20 VALU ops, no LDS.
__device__ __forceinline__ int nth_set_bit(unsigned long long m, int j) {
  int pos = 0;
  unsigned int w = (unsigned int)m;
  int c = __popc(w);
  if (j >= c) { j -= c; w = (unsigned int)(m >> 32); pos = 32; }
  c = __popc(w & 0xFFFFu); if (j >= c) { j -= c; w >>= 16; pos += 16; }
  c = __popc(w & 0xFFu);   if (j >= c) { j -= c; w >>= 8;  pos += 8; }
  c = __popc(w & 0xFu);    if (j >= c) { j -= c; w >>= 4;  pos += 4; }
  c = __popc(w & 0x3u);    if (j >= c) { j -= c; w >>= 2;  pos += 2; }
  c = __popc(w & 0x1u);    if (j >= c) { pos += 1; }
  return pos;
}

// ---------------------------------------------------------------------------
// One fg element processed cooperatively by a 4-lane team.
// sub in [0,4): lane's role. Work split: clip edge pair (1 P-edge + 1
// Q-edge), one of 4 DFL softmax rows, 20 of 80 score floats. Partials are
// combined with intra-quad shfl_xor butterflies (quads are lane-aligned).
// ---------------------------------------------------------------------------
__device__ __forceinline__ void team_elem(
    int idx, int sub,
    const float* __restrict__ pred_dist,
    const float* __restrict__ pred_bboxes,
    const float* __restrict__ pred_angles,
    const float* __restrict__ anchor_points,
    const float* __restrict__ target_bboxes,
    const float* __restrict__ target_angles,
    const float* __restrict__ target_scores,
    float& ci, float& cd) {
  const int l = idx % LL;
  const float4 pb = ((const float4*)pred_bboxes)[idx];
  const float4 tb = ((const float4*)target_bboxes)[idx];
  const float kD2R = 0.017453292519943295f;
  float sp, cp, st, ct;
  __sincosf(pred_angles[idx] * kD2R, &sp, &cp);
  __sincosf(target_angles[idx] * kD2R, &st, &ct);

  // corners (CCW), frame centered on pred box center (replicated on team)
  const float tx[4] = {0.5f, -0.5f, -0.5f, 0.5f};
  const float ty[4] = {0.5f, 0.5f, -0.5f, -0.5f};
  const float qcx = tb.x - pb.x, qcy = tb.y - pb.y;
  float pxx[4], pyy[4], qxx[4], qyy[4];
#pragma unroll
  for (int k = 0; k < 4; ++k) {
    float lx = tx[k] * pb.z, ly = ty[k] * pb.w;
    pxx[k] = lx * cp - ly * sp;
    pyy[k] = lx * sp + ly * cp;
    lx = tx[k] * tb.z; ly = ty[k] * tb.w;
    qxx[k] = lx * ct - ly * st + qcx;
    qyy[k] = lx * st + ly * ct + qcy;
  }
  // inward half-plane normals (replicated; statically indexed everywhere)
  float pnx[4], pny[4], pof[4], qnx[4], qny[4], qof[4];
#pragma unroll
  for (int k = 0; k < 4; ++k) {
    const int kp = (k + 1) & 3;
    pnx[k] = pyy[k] - pyy[kp]; pny[k] = pxx[kp] - pxx[k];
    pof[k] = pnx[k] * pxx[k] + pny[k] * pyy[k];
    qnx[k] = qyy[k] - qyy[kp]; qny[k] = qxx[kp] - qxx[k];
    qof[k] = qnx[k] * qxx[k] + qny[k] * qyy[k];
  }

  // --- this lane's two clip edges (endpoints via cndmask selects) ---
  const int subp = (sub + 1) & 3;
  const float pax = sel4(pxx[0], pxx[1], pxx[2], pxx[3], sub);
  const float pay = sel4(pyy[0], pyy[1], pyy[2], pyy[3], sub);
  const float pbx = sel4(pxx[0], pxx[1], pxx[2], pxx[3], subp);
  const float pby = sel4(pyy[0], pyy[1], pyy[2], pyy[3], subp);
  const float qax = sel4(qxx[0], qxx[1], qxx[2], qxx[3], sub);
  const float qay = sel4(qyy[0], qyy[1], qyy[2], qyy[3], sub);
  const float qbx = sel4(qxx[0], qxx[1], qxx[2], qxx[3], subp);
  const float qby = sel4(qyy[0], qyy[1], qyy[2], qyy[3], subp);
  float s2 = clip_piece<false>(pax, pay, pbx, pby, qnx, qny, qof) +
             clip_piece<true>(qax, qay, qbx, qby, pnx, pny, pof);
  s2 += __shfl_xor(s2, 1);
  s2 += __shfl_xor(s2, 2);

  const float inter = 0.5f * fabsf(s2);
  const float a1 = pb.z * pb.w, a2 = tb.z * tb.w;
  const float iou = fmaxf(inter / (a1 + a2 - inter + 1e-8f), 1e-6f);
  const float iou_loss = 1.f - iou;

  // --- bbox_weight: 20 of 80 scores per lane ---
  const float4* sp4 = (const float4*)(target_scores + (size_t)idx * NCLS) + sub * 5;
  float bw = 0.f;
#pragma unroll
  for (int k = 0; k < 5; ++k) {
    const float4 v = sp4[k];
    bw += (v.x + v.y) + (v.z + v.w);
  }
  bw += __shfl_xor(bw, 1);
  bw += __shfl_xor(bw, 2);

  // --- DFL: row s == sub per lane ---
  const float2 anc = ((const float2*)anchor_points)[l];
  const float d0 = anc.x - tb.x, d1 = anc.y - tb.y;
  const float d2 = tb.z - anc.x, d3 = tb.w - anc.y;
  const float t = fminf(fmaxf(sel4(d0, d1, d2, d3, sub), 0.f), 15.99f);
  const float* row = pred_dist + (size_t)idx * 68 + sub * 17;
  float vv[17];
#pragma unroll
  for (int k = 0; k < 17; ++k) vv[k] = row[k];
  float mx = vv[0];
#pragma unroll
  for (int k = 1; k < 17; ++k) mx = fmaxf(mx, vv[k]);
  const float kLog2e = 1.4426950408889634f;
  const float kLn2 = 0.6931471805599453f;
  float se = 0.f;
#pragma unroll
  for (int k = 0; k < 17; ++k) se += exp2f((vv[k] - mx) * kLog2e);
  const float lz = mx + log2f(se) * kLn2;
  int tl = (int)t;
  tl = tl < 0 ? 0 : (tl > 15 ? 15 : tl);
  const float wl = (float)(tl + 1) - t;
  const float wr = 1.f - wl;
  // register select-chain instead of dependent L1 re-reads
  float vtl = vv[0], vtl1 = vv[1];
#pragma unroll
  for (int k = 1; k < 16; ++k) {
    vtl  = (k == tl) ? vv[k]     : vtl;
    vtl1 = (k == tl) ? vv[k + 1] : vtl1;
  }
  float dfl = -((vtl - lz) * wl + (vtl1 - lz) * wr);
  dfl += __shfl_xor(dfl, 1);
  dfl += __shfl_xor(dfl, 2);
  dfl *= 0.25f;

  if (sub == 0) {
    ci = fmaf(iou_loss, bw, ci);
    cd = fmaf(dfl, bw, cd);
  }
}

// ---------------------------------------------------------------------------
// Main kernel: one wave per 64 elements (2688 waves -> ~10.5 waves/CU).
// fg set = __ballot of own-element mask; 16 four-lane teams pick the j-th
// set bit via popc binary search (no LDS, no prefix scan on the chain).
// Mask layout detected from a fixed 256-byte window (L2-hot, global-safe).
// ---------------------------------------------------------------------------
__global__ __launch_bounds__(64) void main_kernel(
    const float* __restrict__ pred_dist,
    const float* __restrict__ pred_bboxes,
    const float* __restrict__ pred_angles,
    const float* __restrict__ anchor_points,
    const float* __restrict__ target_bboxes,
    const float* __restrict__ target_angles,
    const float* __restrict__ target_scores,
    const void* __restrict__ fgp,
    float2* __restrict__ partials) {
  const int blk = blockIdx.x;
  const int lane = threadIdx.x;
  const int base = blk * EPB;

  // ---- layout detection from fixed window: bytes [0, 256) ----
  unsigned int x = ((const unsigned int*)fgp)[lane];
#pragma unroll
  for (int o = 32; o >= 1; o >>= 1) x |= __shfl_xor(x, o);
  // byte-layout iff OR has only 0x01 bytes and a set bit beyond bit 0
  const bool isByte = ((x & ~0x01010101u) == 0u) && (x > 1u);

  // ---- own-element mask read ----
  bool fg;
  if (isByte) {
    fg = ((const unsigned char*)fgp)[base + lane] != 0;
  } else {
    // 4-byte layout (int32 or float32: !=0 correct for both)
    fg = ((const unsigned int*)fgp)[base + lane] != 0u;
  }
  const unsigned long long m = __ballot(fg);
  const int total = __popcll(m);

  const int team = lane >> 2, sub = lane & 3;
  float ci = 0.f, cd = 0.f;
  for (int j = team; j < total; j += 16) {   // uniform across each quad
    const int e = nth_set_bit(m, j);
    team_elem(base + e, sub, pred_dist, pred_bboxes, pred_angles,
              anchor_points, target_bboxes, target_angles, target_scores,
              ci, cd);
  }
#pragma unroll
  for (int o = 32; o >= 1; o >>= 1) {
    ci += __shfl_xor(ci, o);
    cd += __shfl_xor(cd, o);
  }
  if (lane == 0) partials[blk] = make_float2(ci, cd);
}

// ---------------------------------------------------------------------------
// Finalize: sum 2688 partials (ceil-strided with bounds guard -- R6's bug
// was NB/256 truncating 10.5 -> 10, dropping 128 partials), divide by tss.
// ---------------------------------------------------------------------------
__global__ __launch_bounds__(256) void final_kernel(
    const float2* __restrict__ partials,
    const float* __restrict__ tss_p,
    float* __restrict__ out) {
  const int t = threadIdx.x;
  float a = 0.f, b = 0.f;
#pragma unroll
  for (int i = 0; i < (NB + 255) / 256; ++i) {
    const int j = t + i * 256;
    if (j < NB) {
      const float2 p = partials[j];
      a += p.x; b += p.y;
    }
  }
#pragma unroll
  for (int o = 32; o >= 1; o >>= 1) {
    a += __shfl_xor(a, o);
    b += __shfl_xor(b, o);
  }
  __shared__ float sa[4], sb[4];
  const int w = t >> 6;
  if ((t & 63) == 0) { sa[w] = a; sb[w] = b; }
  __syncthreads();
  if (t == 0) {
    const float s0 = (sa[0] + sa[1]) + (sa[2] + sa[3]);
    const float s1 = (sb[0] + sb[1]) + (sb[2] + sb[3]);
    const float ts = tss_p[0];
    const float denom = (ts == 0.f) ? 1.f : ts;
    out[0] = s0 / denom;
    out[1] = s1 / denom;
  }
}

extern "C" void kernel_launch(void* const* d_in, const int* in_sizes, int n_in,
                              void* d_out, int out_size, void* d_ws, size_t ws_size,
                              hipStream_t stream) {
  const float* pred_dist      = (const float*)d_in[0];
  const float* pred_bboxes    = (const float*)d_in[1];
  const float* pred_angles    = (const float*)d_in[2];
  const float* anchor_points  = (const float*)d_in[3];
  const float* target_bboxes  = (const float*)d_in[4];
  const float* target_angles  = (const float*)d_in[5];
  const float* target_scores  = (const float*)d_in[6];
  const float* tss            = (const float*)d_in[7];
  const void*  fgp            = d_in[8];

  float2* partials = (float2*)d_ws;
  float* out = (float*)d_out;

  main_kernel<<<NB, 64, 0, stream>>>(pred_dist, pred_bboxes, pred_angles,
                                     anchor_points, target_bboxes, target_angles,
                                     target_scores, fgp, partials);
  final_kernel<<<1, 256, 0, stream>>>(partials, tss, out);
}